// Round 8
// baseline (100.246 us; speedup 1.0000x reference)
//
#include <hip/hip_runtime.h>

// out[b,o] = (rowsum(x)[b] + rowsum(w)[o]) * bias[o]
// B=8192, IN=2048, OUT=2048, all float32.
//
// ONE kernel, 512 blocks x 256 threads, co-resident by capacity
// (__launch_bounds__(256,2): >=2 blocks/CU x 256 CUs = 512 slots).
// Per wave: reduce 1 w-row -> wsb (publish; one release-arrive per BLOCK),
// reduce 4 x-rows into regs (hides the producer window), then a cheap
// barrier: RELAXED poll by tid0 only + one acquire fence (R5's failure was
// acquire-per-poll from 2048 waves), then stream 4 out-rows per wave.

#define B_DIM 8192
#define IN_DIM 2048
#define OUT_DIM 2048
#define NBLK 512u

typedef float f32x4 __attribute__((ext_vector_type(4)));

__device__ __forceinline__ float butterfly_reduce(float s) {
    #pragma unroll
    for (int off = 32; off; off >>= 1)
        s += __shfl_xor(s, off, 64);
    return s;   // result in all 64 lanes
}

__device__ __forceinline__ float row_reduce(const float* __restrict__ row, int lane) {
    const f32x4* r4 = reinterpret_cast<const f32x4*>(row);
    f32x4 v[8];
    #pragma unroll
    for (int k = 0; k < 8; ++k)
        v[k] = r4[lane + (k << 6)];
    float s = 0.f;
    #pragma unroll
    for (int k = 0; k < 8; ++k)
        s += (v[k].x + v[k].y) + (v[k].z + v[k].w);
    return butterfly_reduce(s);
}

__global__ __launch_bounds__(256, 2) void fused_all(const float* __restrict__ x,
                                                    const float* __restrict__ w,
                                                    const float* __restrict__ bias,
                                                    float* __restrict__ out,
                                                    float* __restrict__ wsb,
                                                    unsigned int* __restrict__ cnt) {
    const int tid  = threadIdx.x;
    const int wave = tid >> 6;
    const int lane = tid & 63;
    const int blk  = blockIdx.x;               // 0 .. 511

    // ---- phase 1: one w-row per wave (2048 rows total) ----
    const int wrow = (blk << 2) + wave;
    float ws_ = row_reduce(w + (size_t)wrow * IN_DIM, lane);
    if (lane == 0)
        wsb[wrow] = ws_ * bias[wrow];

    // ---- arrive: ONE release-add per block ----
    __syncthreads();                           // all 4 waves' wsb stores issued
    if (tid == 0) {
        __threadfence();                       // release: wsb visible device-wide
        atomicAdd(cnt, 1u);                    // device-scope arrive
    }

    // ---- phase 2: 4 x-rows per wave into registers (overlaps producers) ----
    const int xbase = blk << 4;                // 16 x-rows per block
    float xs[4];
    #pragma unroll
    for (int r = 0; r < 4; ++r)
        xs[r] = row_reduce(x + (size_t)(xbase + (r << 2) + wave) * IN_DIM, lane);

    // ---- barrier: relaxed poll by tid0 only, fence once (expected ~0 spins) ----
    if (tid == 0) {
        while (__hip_atomic_load(cnt, __ATOMIC_RELAXED, __HIP_MEMORY_SCOPE_AGENT) < NBLK)
            __builtin_amdgcn_s_sleep(16);
    }
    __syncthreads();
    __threadfence();                           // acquire: fresh wsb/bias reads

    // ---- phase 3: write 4 out-rows per wave ----
    const f32x4* bias4 = reinterpret_cast<const f32x4*>(bias);
    const f32x4* wsb4  = reinterpret_cast<const f32x4*>(wsb);
    #pragma unroll
    for (int r = 0; r < 4; ++r) {
        const int row = xbase + (r << 2) + wave;
        f32x4* orow = reinterpret_cast<f32x4*>(out) + (size_t)row * (OUT_DIM / 4);
        const float v = xs[r];
        #pragma unroll
        for (int k = 0; k < 8; ++k) {
            const int i = lane + (k << 6);
            const f32x4 bi = bias4[i];         // L1-resident after first row
            const f32x4 wv = wsb4[i];
            f32x4 o;
            o.x = fmaf(v, bi.x, wv.x);
            o.y = fmaf(v, bi.y, wv.y);
            o.z = fmaf(v, bi.z, wv.z);
            o.w = fmaf(v, bi.w, wv.w);
            orow[i] = o;
        }
    }
}

extern "C" void kernel_launch(void* const* d_in, const int* in_sizes, int n_in,
                              void* d_out, int out_size, void* d_ws, size_t ws_size,
                              hipStream_t stream) {
    const float* x    = (const float*)d_in[0];   // [8192, 2048]
    const float* w    = (const float*)d_in[1];   // [2048, 2048]
    const float* bias = (const float*)d_in[2];   // [2048]
    float* out = (float*)d_out;                  // [8192, 2048]

    unsigned int* cnt = (unsigned int*)d_ws;             // arrive counter
    float* wsb = (float*)((char*)d_ws + 256);            // 2048 floats

    hipMemsetAsync(d_ws, 0, 4, stream);                  // zero counter every call

    fused_all<<<NBLK, 256, 0, stream>>>(x, w, bias, out, wsb, cnt);
}

// Round 9
// 82.792 us; speedup vs baseline: 1.2108x; 1.2108x over previous
//
#include <hip/hip_runtime.h>

// out[b,o] = (rowsum(x)[b] + rowsum(w)[o]) * bias[o]
// B=8192, IN=2048, OUT=2048, all float32.
//
// ONE kernel, 1024 blocks x 256 (4 waves). __launch_bounds__(256,8) caps
// VGPR<=64 -> 8 blocks/CU capacity = 2048 slots; 1024 blocks co-resident
// with 2x margin (no exact-fit deadlock risk).
//
// ZERO fences (R5/R8 lesson: agent-scope __threadfence = L2 cache ops on
// 8 XCDs; executed per-thread it is a 100+ us disaster). Instead:
//  - producer: wsb[wr] published via RELAXED agent-scope atomic store
//    (write-through past the XCD L2 to the device coherence point),
//    s_waitcnt vmcnt(0), then RELAXED agent fetch_add arrive (no return use).
//  - consumer: RELAXED agent atomic poll of cnt + s_sleep, __syncthreads,
//    then PLAIN vector loads of wsb: safe because no consumer-XCD L2 line
//    for wsb can pre-exist (nothing read wsb pre-poll this kernel; dispatch
//    -start invalidate cleared prior kernels' lines), so the miss fetches
//    the written-through value; cross-replay staleness is value-identical.

#define B_DIM 8192
#define IN_DIM 2048
#define OUT_DIM 2048
#define NBLK 1024
#define W_TOTAL 2048u

typedef float f32x4 __attribute__((ext_vector_type(4)));

__device__ __forceinline__ float butterfly_reduce(float s) {
    #pragma unroll
    for (int off = 32; off; off >>= 1)
        s += __shfl_xor(s, off, 64);
    return s;   // result in all 64 lanes
}

__device__ __forceinline__ float row_reduce(const float* __restrict__ row, int lane) {
    const f32x4* r4 = reinterpret_cast<const f32x4*>(row);
    f32x4 v[8];
    #pragma unroll
    for (int k = 0; k < 8; ++k)
        v[k] = r4[lane + (k << 6)];
    float s = 0.f;
    #pragma unroll
    for (int k = 0; k < 8; ++k)
        s += (v[k].x + v[k].y) + (v[k].z + v[k].w);
    return butterfly_reduce(s);
}

__global__ __launch_bounds__(256, 8) void fused_all(const float* __restrict__ x,
                                                    const float* __restrict__ w,
                                                    const float* __restrict__ bias,
                                                    float* __restrict__ out,
                                                    float* __restrict__ wsb,
                                                    unsigned int* __restrict__ cnt) {
    const int tid  = threadIdx.x;
    const int wave = tid >> 6;
    const int lane = tid & 63;
    const int blk  = blockIdx.x;               // 0 .. 1023

    // ---- phase 1: waves 0,1 each reduce one w-row and publish ----
    if (wave < 2) {
        const int wr = (blk << 1) + wave;      // 0 .. 2047
        float s = row_reduce(w + (size_t)wr * IN_DIM, lane);
        if (lane == 0) {
            // write-through publish (bypasses this XCD's L2)
            __hip_atomic_store(&wsb[wr], s * bias[wr],
                               __ATOMIC_RELAXED, __HIP_MEMORY_SCOPE_AGENT);
            asm volatile("s_waitcnt vmcnt(0)" ::: "memory");   // store at IC
            (void)__hip_atomic_fetch_add(cnt, 1u, __ATOMIC_RELAXED,
                                         __HIP_MEMORY_SCOPE_AGENT);
        }
    }

    // ---- phase 2: every wave reduces 2 x-rows into registers ----
    const int xbase = (blk << 3) + (wave << 1);        // 8 rows/block, 2/wave
    float xs0 = row_reduce(x + (size_t)xbase * IN_DIM, lane);
    float xs1 = row_reduce(x + (size_t)(xbase + 1) * IN_DIM, lane);

    // ---- barrier: relaxed poll (expected ~0 spins: producers done ~3us,
    //      consumers arrive here ~13us) ----
    if (tid == 0) {
        while (__hip_atomic_load(cnt, __ATOMIC_RELAXED,
                                 __HIP_MEMORY_SCOPE_AGENT) < W_TOTAL)
            __builtin_amdgcn_s_sleep(8);
    }
    __syncthreads();                           // orders post-poll loads, no fence

    // ---- phase 3: write 2 out rows per wave ----
    const f32x4* bias4 = reinterpret_cast<const f32x4*>(bias);
    const f32x4* wsb4  = reinterpret_cast<const f32x4*>(wsb);
    #pragma unroll
    for (int r = 0; r < 2; ++r) {
        const float v = r ? xs1 : xs0;
        f32x4* orow = reinterpret_cast<f32x4*>(out)
                    + (size_t)(xbase + r) * (OUT_DIM / 4);
        #pragma unroll
        for (int k = 0; k < 8; ++k) {
            const int i = lane + (k << 6);
            const f32x4 bi = bias4[i];         // cached (input, never stale)
            const f32x4 wv = wsb4[i];          // safe plain load (see header)
            f32x4 o;
            o.x = fmaf(v, bi.x, wv.x);
            o.y = fmaf(v, bi.y, wv.y);
            o.z = fmaf(v, bi.z, wv.z);
            o.w = fmaf(v, bi.w, wv.w);
            orow[i] = o;
        }
    }
}

extern "C" void kernel_launch(void* const* d_in, const int* in_sizes, int n_in,
                              void* d_out, int out_size, void* d_ws, size_t ws_size,
                              hipStream_t stream) {
    const float* x    = (const float*)d_in[0];   // [8192, 2048]
    const float* w    = (const float*)d_in[1];   // [2048, 2048]
    const float* bias = (const float*)d_in[2];   // [2048]
    float* out = (float*)d_out;                  // [8192, 2048]

    unsigned int* cnt = (unsigned int*)d_ws;             // arrive counter
    float* wsb = (float*)((char*)d_ws + 256);            // 2048 floats

    hipMemsetAsync(d_ws, 0, 4, stream);                  // zero counter every call

    fused_all<<<NBLK, 256, 0, stream>>>(x, w, bias, out, wsb, cnt);
}

// Round 10
// 33.540 us; speedup vs baseline: 2.9888x; 2.4685x over previous
//
#include <hip/hip_runtime.h>

// out[b,o] = (rowsum(x)[b] + rowsum(w)[o]) * bias[o]
// B=8192, IN=2048, OUT=2048, all float32.
//
// ONE fused kernel + one 8-KB memset node. No atomic RMW, no fences, no
// shared counter (R5/R8/R9 lesson: 512-2048 same-line RMW arrivals serialize
// ~30ns each at the coherence point = 60+ us; per-thread agent fences are
// similarly fatal). Sync = sentinel-poll on the DATA:
//  - memset wsb to 0xFF (sentinel NaN pattern; finite inputs can't produce it)
//  - producers: relaxed agent-scope atomic STORES of wsb (write-through,
//    2048 independent lines, no serialization)
//  - consumers: after their x-phase (~12us, >> producer finish ~3us), each
//    block verifies all 2048 words via coalesced relaxed agent atomic loads
//    (thread tid checks tid+m*256) in a __syncthreads_and retry loop
//    (expected 1 iteration). Plain cached reads of wsb afterwards are safe:
//    dispatch-start invalidate kills pre-kernel lines; in-kernel lines only
//    arise from post-confirmation loads.
// Co-residency by capacity: 512 blocks, __launch_bounds__(256,2) -> >=2
// blocks/CU x 256 CUs = 512 slots; every block produces before it polls.

#define B_DIM 8192
#define IN_DIM 2048
#define OUT_DIM 2048
#define NBLK 512
#define SENT 0xFFFFFFFFu

typedef float f32x4 __attribute__((ext_vector_type(4)));

__device__ __forceinline__ float butterfly_reduce(float s) {
    #pragma unroll
    for (int off = 32; off; off >>= 1)
        s += __shfl_xor(s, off, 64);
    return s;   // result in all 64 lanes
}

__device__ __forceinline__ float row_reduce(const float* __restrict__ row, int lane) {
    const f32x4* r4 = reinterpret_cast<const f32x4*>(row);
    f32x4 v[8];
    #pragma unroll
    for (int k = 0; k < 8; ++k)
        v[k] = r4[lane + (k << 6)];
    float s = 0.f;
    #pragma unroll
    for (int k = 0; k < 8; ++k)
        s += (v[k].x + v[k].y) + (v[k].z + v[k].w);
    return butterfly_reduce(s);
}

__global__ __launch_bounds__(256, 2) void fused_all(const float* __restrict__ x,
                                                    const float* __restrict__ w,
                                                    const float* __restrict__ bias,
                                                    float* __restrict__ out,
                                                    float* __restrict__ wsb) {
    const int tid  = threadIdx.x;
    const int wave = tid >> 6;
    const int lane = tid & 63;
    const int blk  = blockIdx.x;               // 0 .. 511

    // ---- phase 1: one w-row per wave (512*4 = 2048 rows) ----
    const int wr = (blk << 2) + wave;
    {
        float s = row_reduce(w + (size_t)wr * IN_DIM, lane);
        if (lane == 0)
            __hip_atomic_store(&wsb[wr], s * bias[wr],
                               __ATOMIC_RELAXED, __HIP_MEMORY_SCOPE_AGENT);
    }

    // ---- phase 2: 4 x-rows per wave into registers (16 rows/block) ----
    const int xbase = blk << 4;
    float xs[4];
    #pragma unroll
    for (int r = 0; r < 4; ++r)
        xs[r] = row_reduce(x + (size_t)(xbase + (r << 2) + wave) * IN_DIM, lane);

    // ---- sync: block-cooperative sentinel poll (expected 1 iteration) ----
    const unsigned* wsb_u = reinterpret_cast<const unsigned*>(wsb);
    int ok;
    do {
        ok = 1;
        #pragma unroll
        for (int m = 0; m < 8; ++m) {
            unsigned u = __hip_atomic_load(&wsb_u[tid + (m << 8)],
                                           __ATOMIC_RELAXED,
                                           __HIP_MEMORY_SCOPE_AGENT);
            ok &= (u != SENT);
        }
        if (!ok) __builtin_amdgcn_s_sleep(8);
    } while (!__syncthreads_and(ok));

    // ---- phase 3: write 4 out-rows per wave (plain cached loads, now safe) ----
    const f32x4* bias4 = reinterpret_cast<const f32x4*>(bias);
    const f32x4* wsb4  = reinterpret_cast<const f32x4*>(wsb);
    #pragma unroll
    for (int r = 0; r < 4; ++r) {
        const int row = xbase + (r << 2) + wave;
        f32x4* orow = reinterpret_cast<f32x4*>(out) + (size_t)row * (OUT_DIM / 4);
        const float v = xs[r];
        #pragma unroll
        for (int k = 0; k < 8; ++k) {
            const int i = lane + (k << 6);
            const f32x4 bi = bias4[i];         // L1-resident after first row
            const f32x4 wv = wsb4[i];
            f32x4 o;
            o.x = fmaf(v, bi.x, wv.x);
            o.y = fmaf(v, bi.y, wv.y);
            o.z = fmaf(v, bi.z, wv.z);
            o.w = fmaf(v, bi.w, wv.w);
            orow[i] = o;
        }
    }
}

extern "C" void kernel_launch(void* const* d_in, const int* in_sizes, int n_in,
                              void* d_out, int out_size, void* d_ws, size_t ws_size,
                              hipStream_t stream) {
    const float* x    = (const float*)d_in[0];   // [8192, 2048]
    const float* w    = (const float*)d_in[1];   // [2048, 2048]
    const float* bias = (const float*)d_in[2];   // [2048]
    float* out = (float*)d_out;                  // [8192, 2048]
    float* wsb = (float*)d_ws;                   // 2048 floats

    // reset sentinel every call (graph-capture-legal)
    hipMemsetAsync(wsb, 0xFF, OUT_DIM * sizeof(float), stream);

    fused_all<<<NBLK, 256, 0, stream>>>(x, w, bias, out, wsb);
}